// Round 1
// baseline (4276.554 us; speedup 1.0000x reference)
//
#include <hip/hip_runtime.h>
#include <cmath>

#define TT    2048
#define CC    768
#define NHEAD 12
#define HDIM  64
#define LWIN  256
#define BBATCH 2
#define MROWS 4096   // B*T
#define QB    32     // query rows per attention block

// ---------------------------------------------------------------- wave reduce
__device__ __forceinline__ float waveReduceMax(float v) {
#pragma unroll
  for (int off = 32; off > 0; off >>= 1) v = fmaxf(v, __shfl_xor(v, off, 64));
  return v;
}
__device__ __forceinline__ float waveReduceSum(float v) {
#pragma unroll
  for (int off = 32; off > 0; off >>= 1) v += __shfl_xor(v, off, 64);
  return v;
}

// ---------------------------------------------------------------- fp32 GEMM
// C[M,N] = A[M,K] @ B[K,N] + bias[N].  M%128==0, N%128==0, K%8==0.
__global__ __launch_bounds__(256) void gemm_bias_kernel(
    const float* __restrict__ A, const float* __restrict__ B,
    const float* __restrict__ bias, float* __restrict__ C,
    int M, int N, int K) {
  __shared__ alignas(16) float As[8][128];
  __shared__ alignas(16) float Bs[8][128];
  const int tid = threadIdx.x;
  const int m0 = blockIdx.y * 128, n0 = blockIdx.x * 128;
  const int tx = tid & 15, ty = tid >> 4;
  const int arow = tid >> 1, acol = (tid & 1) << 2;
  const int brow = tid >> 5, bcol = (tid & 31) << 2;

  float acc[8][8];
#pragma unroll
  for (int i = 0; i < 8; ++i)
#pragma unroll
    for (int j = 0; j < 8; ++j) acc[i][j] = 0.f;

  for (int k0 = 0; k0 < K; k0 += 8) {
    const float4 av = *(const float4*)&A[(size_t)(m0 + arow) * K + k0 + acol];
    const float4 bv = *(const float4*)&B[(size_t)(k0 + brow) * N + n0 + bcol];
    __syncthreads();
    As[acol + 0][arow] = av.x;
    As[acol + 1][arow] = av.y;
    As[acol + 2][arow] = av.z;
    As[acol + 3][arow] = av.w;
    *(float4*)&Bs[brow][bcol] = bv;
    __syncthreads();
#pragma unroll
    for (int kk = 0; kk < 8; ++kk) {
      float a[8], b[8];
      *(float4*)&a[0] = *(const float4*)&As[kk][ty << 3];
      *(float4*)&a[4] = *(const float4*)&As[kk][(ty << 3) + 4];
      *(float4*)&b[0] = *(const float4*)&Bs[kk][tx << 3];
      *(float4*)&b[4] = *(const float4*)&Bs[kk][(tx << 3) + 4];
#pragma unroll
      for (int i = 0; i < 8; ++i)
#pragma unroll
        for (int j = 0; j < 8; ++j) acc[i][j] = fmaf(a[i], b[j], acc[i][j]);
    }
  }
#pragma unroll
  for (int i = 0; i < 8; ++i) {
    const int row = m0 + (ty << 3) + i;
#pragma unroll
    for (int j4 = 0; j4 < 2; ++j4) {
      const int col = n0 + (tx << 3) + (j4 << 2);
      float4 o;
      o.x = acc[i][j4 * 4 + 0] + bias[col + 0];
      o.y = acc[i][j4 * 4 + 1] + bias[col + 1];
      o.z = acc[i][j4 * 4 + 2] + bias[col + 2];
      o.w = acc[i][j4 * 4 + 3] + bias[col + 3];
      *(float4*)&C[(size_t)row * N + col] = o;
    }
  }
}

// ---------------------------------------------------------------- selectivity gate
// gate[r] = 0.2 + 0.8*sigmoid( gelu(x_r @ w1 + b1) @ w2 + b2 ),  8 rows/block
__global__ __launch_bounds__(256) void sel_kernel(
    const float* __restrict__ x, const float* __restrict__ w1,
    const float* __restrict__ b1, const float* __restrict__ w2,
    const float* __restrict__ b2, float* __restrict__ gate) {
  __shared__ alignas(16) float xs[8][768];
  __shared__ float gh[8][192];
  const int r0 = blockIdx.x * 8;
  const int tid = threadIdx.x;
#pragma unroll
  for (int idx = tid; idx < 8 * 192; idx += 256) {   // 8*768/4 float4 loads
    const int r = idx / 192, d4 = idx % 192;
    *(float4*)&xs[r][d4 << 2] =
        *(const float4*)&x[(size_t)(r0 + r) * 768 + (d4 << 2)];
  }
  __syncthreads();
  if (tid < 192) {
    float h[8];
#pragma unroll
    for (int r = 0; r < 8; ++r) h[r] = b1[tid];
#pragma unroll 4
    for (int d = 0; d < 768; ++d) {
      const float w = w1[d * 192 + tid];
#pragma unroll
      for (int r = 0; r < 8; ++r) h[r] = fmaf(xs[r][d], w, h[r]);
    }
#pragma unroll
    for (int r = 0; r < 8; ++r) {
      const float v = h[r];
      gh[r][tid] = 0.5f * v * (1.f + erff(v * 0.70710678118654752f));
    }
  }
  __syncthreads();
  if (tid < 8) {
    float s = b2[0];
    for (int j = 0; j < 192; ++j) s = fmaf(gh[tid][j], w2[j], s);
    const float sel = 1.f / (1.f + __expf(-s));
    gate[r0 + tid] = 0.2f + 0.8f * sel;
  }
}

// ---------------------------------------------------------------- fused attention
// Two online-softmax streams per query row:
//   stream1 (local):  raw scores, keys in [max(i-LWIN,0), i]
//   stream2 (global): scores * gate[key], keys in [0, i]
// out_row = wl*acc1/l1 + wg*acc2/l2, written as [B,T,NH*HD].
__global__ __launch_bounds__(256) void attn_kernel(
    const float* __restrict__ qkv, const float* __restrict__ gate,
    const float* __restrict__ lwp, const float* __restrict__ gwp,
    float* __restrict__ attnout) {
  __shared__ alignas(16) float q_s[QB * 64];
  __shared__ alignas(16) float k_s[64 * 64];   // XOR-swizzled 16B blocks
  __shared__ alignas(16) float v_s[64 * 64];
  __shared__ alignas(16) float p1_s[QB * 64];
  __shared__ alignas(16) float p2_s[QB * 64];
  __shared__ float scl1_s[QB];
  __shared__ float scl2_s[QB];

  const int tid = threadIdx.x;
  const int lane = tid & 63;
  const int wv = tid >> 6;             // wave 0..3; wave owns rows rl = rr*4+wv
  const int bh = blockIdx.y;
  const int bb = bh / NHEAD;
  const int hh = bh % NHEAD;
  const int r0 = blockIdx.x * QB;

  // stage Q rows [r0, r0+QB)
#pragma unroll
  for (int idx = tid; idx < QB * 16; idx += 256) {
    const int r = idx >> 4, d4 = idx & 15;
    *(float4*)&q_s[(r << 6) + (d4 << 2)] =
        *(const float4*)&qkv[(size_t)(bb * TT + r0 + r) * 2304 + hh * 64 + (d4 << 2)];
  }

  float m1[8], l1[8], m2[8], l2[8], a1[8], a2[8];
#pragma unroll
  for (int rr = 0; rr < 8; ++rr) {
    m1[rr] = -1e30f; m2[rr] = -1e30f;
    l1[rr] = 0.f; l2[rr] = 0.f; a1[rr] = 0.f; a2[rr] = 0.f;
  }

  const int nt = (r0 + QB + 63) >> 6;
  for (int t = 0; t < nt; ++t) {
    const int t0 = t << 6;
    __syncthreads();                       // previous tile's LDS reads done
    // stage K (swizzled) and V, 64 keys x 64 dims
#pragma unroll
    for (int idx = tid; idx < 64 * 16; idx += 256) {
      const int j = idx >> 4, d4 = idx & 15;
      const size_t base = (size_t)(bb * TT + t0 + j) * 2304 + hh * 64 + (d4 << 2);
      const float4 kv4 = *(const float4*)&qkv[base + 768];
      const float4 vv4 = *(const float4*)&qkv[base + 1536];
      *(float4*)&k_s[(j << 6) + ((d4 ^ (j & 7)) << 2)] = kv4;
      *(float4*)&v_s[(j << 6) + (d4 << 2)] = vv4;
    }
    __syncthreads();

    const float g = gate[bb * TT + t0 + lane];
    const int jkey = t0 + lane;

    // ---- phase A: lane = key, compute scores for this wave's 8 rows
    float s[8];
#pragma unroll
    for (int rr = 0; rr < 8; ++rr) s[rr] = 0.f;
#pragma unroll
    for (int d0 = 0; d0 < 16; ++d0) {
      const float4 kv = *(const float4*)&k_s[(lane << 6) + ((d0 ^ (lane & 7)) << 2)];
#pragma unroll
      for (int rr = 0; rr < 8; ++rr) {
        const int rl = (rr << 2) + wv;
        const float4 qv = *(const float4*)&q_s[(rl << 6) + (d0 << 2)];
        s[rr] = fmaf(kv.x, qv.x, s[rr]);
        s[rr] = fmaf(kv.y, qv.y, s[rr]);
        s[rr] = fmaf(kv.z, qv.z, s[rr]);
        s[rr] = fmaf(kv.w, qv.w, s[rr]);
      }
    }
#pragma unroll
    for (int rr = 0; rr < 8; ++rr) {
      const int rl = (rr << 2) + wv;
      const int i = r0 + rl;
      const float sv = s[rr] * 0.125f;            // HD^-0.5
      const bool cv = (jkey <= i);
      int lo = i - LWIN; lo = lo < 0 ? 0 : lo;
      const bool lv = cv && (jkey >= lo);
      const float sg = cv ? sv * g : -1e30f;
      const float sl = lv ? sv : -1e30f;
      const float Mg = waveReduceMax(sg);
      const float Ml = waveReduceMax(sl);
      const float m2n = fmaxf(m2[rr], Mg);
      const float m1n = fmaxf(m1[rr], Ml);
      const float p2 = cv ? __expf(sg - m2n) : 0.f;   // explicit mask: no -BIG-(-BIG) trap
      const float p1 = lv ? __expf(sl - m1n) : 0.f;
      const float sc2 = __expf(m2[rr] - m2n);
      const float sc1 = __expf(m1[rr] - m1n);
      l2[rr] = l2[rr] * sc2 + waveReduceSum(p2);
      l1[rr] = l1[rr] * sc1 + waveReduceSum(p1);
      m2[rr] = m2n; m1[rr] = m1n;
      p1_s[(rl << 6) + lane] = p1;
      p2_s[(rl << 6) + lane] = p2;
      if (lane == 0) { scl1_s[rl] = sc1; scl2_s[rl] = sc2; }
    }

    // ---- phase B: lane = d.  Same wave wrote its rows' p/scl: no barrier needed.
    float vcol[64];
#pragma unroll
    for (int jj = 0; jj < 64; ++jj) vcol[jj] = v_s[(jj << 6) + lane];
#pragma unroll
    for (int rr = 0; rr < 8; ++rr) {
      const int rl = (rr << 2) + wv;
      float x1 = a1[rr] * scl1_s[rl];
      float x2 = a2[rr] * scl2_s[rl];
#pragma unroll
      for (int j4 = 0; j4 < 16; ++j4) {
        const float4 pv1 = *(const float4*)&p1_s[(rl << 6) + (j4 << 2)];
        const float4 pv2 = *(const float4*)&p2_s[(rl << 6) + (j4 << 2)];
        x1 = fmaf(pv1.x, vcol[4 * j4 + 0], x1);
        x1 = fmaf(pv1.y, vcol[4 * j4 + 1], x1);
        x1 = fmaf(pv1.z, vcol[4 * j4 + 2], x1);
        x1 = fmaf(pv1.w, vcol[4 * j4 + 3], x1);
        x2 = fmaf(pv2.x, vcol[4 * j4 + 0], x2);
        x2 = fmaf(pv2.y, vcol[4 * j4 + 1], x2);
        x2 = fmaf(pv2.z, vcol[4 * j4 + 2], x2);
        x2 = fmaf(pv2.w, vcol[4 * j4 + 3], x2);
      }
      a1[rr] = x1; a2[rr] = x2;
    }
  }

  // combine the two streams with normalized sigmoid weights
  const float wlr = 1.f / (1.f + __expf(-lwp[0]));
  const float wgr = 1.f / (1.f + __expf(-gwp[0]));
  const float wl = wlr / (wlr + wgr);
  const float wg = wgr / (wlr + wgr);
#pragma unroll
  for (int rr = 0; rr < 8; ++rr) {
    const int rl = (rr << 2) + wv;
    const int i = r0 + rl;
    const float o = wl * a1[rr] / l1[rr] + wg * a2[rr] / l2[rr];
    attnout[(size_t)(bb * TT + i) * CC + hh * 64 + lane] = o;
  }
}

// ---------------------------------------------------------------- launch
extern "C" void kernel_launch(void* const* d_in, const int* in_sizes, int n_in,
                              void* d_out, int out_size, void* d_ws, size_t ws_size,
                              hipStream_t stream) {
  const float* x      = (const float*)d_in[0];
  const float* w_attn = (const float*)d_in[1];
  const float* b_attn = (const float*)d_in[2];
  const float* w_proj = (const float*)d_in[3];
  const float* b_proj = (const float*)d_in[4];
  const float* w_sel1 = (const float*)d_in[5];
  const float* b_sel1 = (const float*)d_in[6];
  const float* w_sel2 = (const float*)d_in[7];
  const float* b_sel2 = (const float*)d_in[8];
  const float* lw     = (const float*)d_in[9];
  const float* gw     = (const float*)d_in[10];
  float* out = (float*)d_out;

  // workspace: qkv [4096,2304] | gate [4096] | attnout [4096,768]  (~48 MB)
  float* qkv     = (float*)d_ws;
  float* gatebuf = qkv + (size_t)MROWS * 2304;
  float* attnout = gatebuf + MROWS;

  gemm_bias_kernel<<<dim3(2304 / 128, MROWS / 128), 256, 0, stream>>>(
      x, w_attn, b_attn, qkv, MROWS, 2304, CC);
  sel_kernel<<<dim3(MROWS / 8), 256, 0, stream>>>(
      x, w_sel1, b_sel1, w_sel2, b_sel2, gatebuf);
  attn_kernel<<<dim3(TT / QB, BBATCH * NHEAD), 256, 0, stream>>>(
      qkv, gatebuf, lw, gw, attnout);
  gemm_bias_kernel<<<dim3(CC / 128, MROWS / 128), 256, 0, stream>>>(
      attnout, w_proj, b_proj, out, MROWS, CC, CC);
}

// Round 4
// 689.445 us; speedup vs baseline: 6.2029x; 6.2029x over previous
//
#include <hip/hip_runtime.h>
#include <cmath>

#define TT    2048
#define CC    768
#define NHEAD 12
#define LWIN  256
#define BBATCH 2
#define MROWS 4096   // B*T
#define QBA   128    // query rows per attention block (4 waves x 32)
#define KB    64     // keys per tile

typedef unsigned int u32;
typedef u32 u32x2 __attribute__((ext_vector_type(2)));
typedef u32 u32x4 __attribute__((ext_vector_type(4)));
typedef short bf16x8 __attribute__((ext_vector_type(8)));
typedef float f32x16 __attribute__((ext_vector_type(16)));

union F4 { u32x4 u; bf16x8 h; };

// round-to-nearest-even f32->bf16
__device__ __forceinline__ unsigned short b16(float a) {
  u32 u = __float_as_uint(a);
  return (unsigned short)((u + 0x7FFFu + ((u >> 16) & 1u)) >> 16);
}
// packed pair (low = first arg)
__device__ __forceinline__ u32 pk2(float a, float b) {
  return (u32)b16(a) | ((u32)b16(b) << 16);
}

// ---------------------------------------------------------------- fp32 GEMM (verified r1)
__global__ __launch_bounds__(256) void gemm_bias_kernel(
    const float* __restrict__ A, const float* __restrict__ B,
    const float* __restrict__ bias, float* __restrict__ C,
    int M, int N, int K) {
  __shared__ alignas(16) float As[8][128];
  __shared__ alignas(16) float Bs[8][128];
  const int tid = threadIdx.x;
  const int m0 = blockIdx.y * 128, n0 = blockIdx.x * 128;
  const int tx = tid & 15, ty = tid >> 4;
  const int arow = tid >> 1, acol = (tid & 1) << 2;
  const int brow = tid >> 5, bcol = (tid & 31) << 2;

  float acc[8][8];
#pragma unroll
  for (int i = 0; i < 8; ++i)
#pragma unroll
    for (int j = 0; j < 8; ++j) acc[i][j] = 0.f;

  for (int k0 = 0; k0 < K; k0 += 8) {
    const float4 av = *(const float4*)&A[(size_t)(m0 + arow) * K + k0 + acol];
    const float4 bv = *(const float4*)&B[(size_t)(k0 + brow) * N + n0 + bcol];
    __syncthreads();
    As[acol + 0][arow] = av.x;
    As[acol + 1][arow] = av.y;
    As[acol + 2][arow] = av.z;
    As[acol + 3][arow] = av.w;
    *(float4*)&Bs[brow][bcol] = bv;
    __syncthreads();
#pragma unroll
    for (int kk = 0; kk < 8; ++kk) {
      float a[8], b[8];
      *(float4*)&a[0] = *(const float4*)&As[kk][ty << 3];
      *(float4*)&a[4] = *(const float4*)&As[kk][(ty << 3) + 4];
      *(float4*)&b[0] = *(const float4*)&Bs[kk][tx << 3];
      *(float4*)&b[4] = *(const float4*)&Bs[kk][(tx << 3) + 4];
#pragma unroll
      for (int i = 0; i < 8; ++i)
#pragma unroll
        for (int j = 0; j < 8; ++j) acc[i][j] = fmaf(a[i], b[j], acc[i][j]);
    }
  }
#pragma unroll
  for (int i = 0; i < 8; ++i) {
    const int row = m0 + (ty << 3) + i;
#pragma unroll
    for (int j4 = 0; j4 < 2; ++j4) {
      const int col = n0 + (tx << 3) + (j4 << 2);
      float4 o;
      o.x = acc[i][j4 * 4 + 0] + bias[col + 0];
      o.y = acc[i][j4 * 4 + 1] + bias[col + 1];
      o.z = acc[i][j4 * 4 + 2] + bias[col + 2];
      o.w = acc[i][j4 * 4 + 3] + bias[col + 3];
      *(float4*)&C[(size_t)row * N + col] = o;
    }
  }
}

// ---------------------------------------------------------------- selectivity gate (verified r1)
__global__ __launch_bounds__(256) void sel_kernel(
    const float* __restrict__ x, const float* __restrict__ w1,
    const float* __restrict__ b1, const float* __restrict__ w2,
    const float* __restrict__ b2, float* __restrict__ gate) {
  __shared__ alignas(16) float xs[8][768];
  __shared__ float gh[8][192];
  const int r0 = blockIdx.x * 8;
  const int tid = threadIdx.x;
#pragma unroll
  for (int idx = tid; idx < 8 * 192; idx += 256) {
    const int r = idx / 192, d4 = idx % 192;
    *(float4*)&xs[r][d4 << 2] =
        *(const float4*)&x[(size_t)(r0 + r) * 768 + (d4 << 2)];
  }
  __syncthreads();
  if (tid < 192) {
    float h[8];
#pragma unroll
    for (int r = 0; r < 8; ++r) h[r] = b1[tid];
#pragma unroll 4
    for (int d = 0; d < 768; ++d) {
      const float w = w1[d * 192 + tid];
#pragma unroll
      for (int r = 0; r < 8; ++r) h[r] = fmaf(xs[r][d], w, h[r]);
    }
#pragma unroll
    for (int r = 0; r < 8; ++r) {
      const float v = h[r];
      gh[r][tid] = 0.5f * v * (1.f + erff(v * 0.70710678118654752f));
    }
  }
  __syncthreads();
  if (tid < 8) {
    float s = b2[0];
    for (int j = 0; j < 192; ++j) s = fmaf(gh[tid][j], w2[j], s);
    const float sel = 1.f / (1.f + __expf(-s));
    gate[r0 + tid] = 0.2f + 0.8f * sel;
  }
}

// ---------------------------------------------------------------- MFMA fused attention
// Swapped QK^T (A=K, B=Q): lane holds S[q=lane&31][key=crow(r,hi)],
// crow=(r&3)+8*(r>>2)+4*hi (hardware-verified C/D layout).
// PV uses slot->key bijection g(hi,e)=16*kb4 + 4*hi + (e&3) + 8*(e>>2):
// valid for ANY hardware A/B k-layout since A and B share the same k-mapping.
//   A-frag (P): regs pa[c][8*h16+e] packed in pairs (in-lane, no shuffles).
//   B-frag (V): V^T in LDS ([64 d][68 u16] padded rows) -> two aligned
//               ds_read_b64 per fragment (keys k0..k0+3 and k0+8..k0+11).
__global__ __launch_bounds__(256) void attn_mfma_kernel(
    const float* __restrict__ qkv, const float* __restrict__ gate,
    const float* __restrict__ lwp, const float* __restrict__ gwp,
    float* __restrict__ attnout) {
  __shared__ alignas(16) unsigned short q_s[QBA * 64];  // bf16, 16B-block XOR swizzle
  __shared__ alignas(16) unsigned short k_s[KB * 64];   // bf16, swizzled
  __shared__ alignas(16) unsigned short vt_s[64 * 68];  // V^T: row=d (68 u16 = 136B)
  __shared__ float g_s[KB];

  const int tid = threadIdx.x;
  const int lane = tid & 63;
  const int wv = tid >> 6;
  const int hi = lane >> 5;
  const int l31 = lane & 31;
  const int bh = blockIdx.y;
  const int bb = bh / NHEAD;
  const int hh = bh % NHEAD;
  const int r0 = blockIdx.x * QBA;
  const int iq = r0 + wv * 32 + l31;      // this lane's softmax row (global)

  // ---- stage Q tile (bf16, swizzled)
#pragma unroll
  for (int idx = tid; idx < QBA * 16; idx += 256) {
    const int r = idx >> 4, d4 = idx & 15;
    const float4 qv =
        *(const float4*)&qkv[(size_t)(bb * TT + r0 + r) * 2304 + hh * 64 + d4 * 4];
    u32x2 w2 = {pk2(qv.x, qv.y), pk2(qv.z, qv.w)};
    const int blk = (d4 >> 1) ^ (r & 7);
    *(u32x2*)((char*)q_s + r * 128 + (blk << 4) + (d4 & 1) * 8) = w2;
  }
  __syncthreads();

  // per-wave Q fragments (B operand: Q[wv*32+l31][16s+8hi+e])
  bf16x8 qf[4];
  {
    const int row = wv * 32 + l31;
#pragma unroll
    for (int s = 0; s < 4; ++s) {
      const int blk = (2 * s + hi) ^ (row & 7);
      F4 f;
      f.u = *(const u32x4*)((const char*)q_s + row * 128 + (blk << 4));
      qf[s] = f.h;
    }
  }

  // per-lane V^T read bases: d = l31 (O-a) and 32+l31 (O-b), +8B for hi
  const char* vb0 = (const char*)vt_s + (size_t)l31 * 136 + hi * 8;
  const char* vb1 = vb0 + 32 * 136;

  float m1 = -1e30f, l1 = 0.f, m2 = -1e30f, l2 = 0.f;
  f32x16 O1a, O1b, O2a, O2b;
#pragma unroll
  for (int r = 0; r < 16; ++r) { O1a[r] = 0.f; O1b[r] = 0.f; O2a[r] = 0.f; O2b[r] = 0.f; }

  const int nt = (r0 + QBA) >> 6;
  for (int t = 0; t < nt; ++t) {
    const int t0 = t << 6;
    __syncthreads();
    // ---- stage K (swizzled), V^T (u16 scatter), gate
#pragma unroll
    for (int idx = tid; idx < KB * 16; idx += 256) {
      const int j = idx >> 4, d4 = idx & 15;
      const size_t base = (size_t)(bb * TT + t0 + j) * 2304 + hh * 64 + d4 * 4;
      const float4 kv = *(const float4*)&qkv[base + 768];
      const float4 vv = *(const float4*)&qkv[base + 1536];
      u32x2 kw = {pk2(kv.x, kv.y), pk2(kv.z, kv.w)};
      const int blk = (d4 >> 1) ^ (j & 7);
      *(u32x2*)((char*)k_s + j * 128 + (blk << 4) + (d4 & 1) * 8) = kw;
      vt_s[(4 * d4 + 0) * 68 + j] = b16(vv.x);
      vt_s[(4 * d4 + 1) * 68 + j] = b16(vv.y);
      vt_s[(4 * d4 + 2) * 68 + j] = b16(vv.z);
      vt_s[(4 * d4 + 3) * 68 + j] = b16(vv.w);
    }
    if (tid < KB) g_s[tid] = gate[bb * TT + t0 + tid];
    __syncthreads();

    // ---- QK^T: S[c] = K(rows 32c..32c+31) . Q^T  (accumulate over 4 d-slices)
    f32x16 S0, S1;
#pragma unroll
    for (int r = 0; r < 16; ++r) { S0[r] = 0.f; S1[r] = 0.f; }
#pragma unroll
    for (int s = 0; s < 4; ++s) {
      const int blk = (2 * s + hi) ^ (l31 & 7);
      F4 f0, f1;
      f0.u = *(const u32x4*)((const char*)k_s + l31 * 128 + (blk << 4));
      f1.u = *(const u32x4*)((const char*)k_s + (32 + l31) * 128 + (blk << 4));
      S0 = __builtin_amdgcn_mfma_f32_32x32x16_bf16(f0.h, qf[s], S0, 0, 0, 0);
      S1 = __builtin_amdgcn_mfma_f32_32x32x16_bf16(f1.h, qf[s], S1, 0, 0, 0);
    }

    // ---- V fragments: per kb4, keys 16kb4+4hi+{0..3} and +8 at fixed d
    F4 va[4], vbf[4];
#pragma unroll
    for (int kb4 = 0; kb4 < 4; ++kb4) {
      const u32x2 a0 = *(const u32x2*)(vb0 + 32 * kb4);
      const u32x2 a1 = *(const u32x2*)(vb0 + 32 * kb4 + 16);
      va[kb4].u = (u32x4){a0.x, a0.y, a1.x, a1.y};
      const u32x2 c0 = *(const u32x2*)(vb1 + 32 * kb4);
      const u32x2 c1 = *(const u32x2*)(vb1 + 32 * kb4 + 16);
      vbf[kb4].u = (u32x4){c0.x, c0.y, c1.x, c1.y};
    }

    // scaled raw scores (keep for stream1)
    float xv[2][16];
#pragma unroll
    for (int r = 0; r < 16; ++r) { xv[0][r] = S0[r] * 0.125f; xv[1][r] = S1[r] * 0.125f; }

    // ================= stream 2: causal, gate-modulated =================
    {
      float pa[2][16];
      float pmax = -1e30f;
#pragma unroll
      for (int c = 0; c < 2; ++c)
#pragma unroll
        for (int r = 0; r < 16; ++r) {
          const int crow = (r & 3) + 8 * (r >> 2) + 4 * hi;
          const int kk = t0 + 32 * c + crow;
          const float g = g_s[32 * c + crow];
          const float v = (kk <= iq) ? xv[c][r] * g : -1e30f;
          pa[c][r] = v;
          pmax = fmaxf(pmax, v);
        }
      pmax = fmaxf(pmax, __shfl_xor(pmax, 32));
      const float mn = fmaxf(m2, pmax);
      const float f = __expf(m2 - mn);
      m2 = mn;
      float sum = 0.f;
#pragma unroll
      for (int c = 0; c < 2; ++c)
#pragma unroll
        for (int r = 0; r < 16; ++r) {
          const float p = (pa[c][r] > -0.5e30f) ? __expf(pa[c][r] - mn) : 0.f;
          pa[c][r] = p;
          sum += p;
        }
      sum += __shfl_xor(sum, 32);
      l2 = l2 * f + sum;
      u32 Pp[2][8];
#pragma unroll
      for (int c = 0; c < 2; ++c)
#pragma unroll
        for (int w = 0; w < 8; ++w)
          Pp[c][w] = pk2(pa[c][2 * w], pa[c][2 * w + 1]);
#pragma unroll
      for (int r = 0; r < 16; ++r) {
        const float fq = __shfl(f, (r & 3) + 8 * (r >> 2) + 4 * hi);
        O2a[r] *= fq;
        O2b[r] *= fq;
      }
#pragma unroll
      for (int c = 0; c < 2; ++c)
#pragma unroll
        for (int h16 = 0; h16 < 2; ++h16) {
          F4 a;
          a.u = (u32x4){Pp[c][4 * h16 + 0], Pp[c][4 * h16 + 1],
                        Pp[c][4 * h16 + 2], Pp[c][4 * h16 + 3]};
          const int kb4 = 2 * c + h16;
          O2a = __builtin_amdgcn_mfma_f32_32x32x16_bf16(a.h, va[kb4].h, O2a, 0, 0, 0);
          O2b = __builtin_amdgcn_mfma_f32_32x32x16_bf16(a.h, vbf[kb4].h, O2b, 0, 0, 0);
        }
    }

    // ================= stream 1: local window, raw scores =================
    if (t0 + 63 >= r0 + wv * 32 - LWIN) {   // wave-uniform window overlap
      float pa[2][16];
      float pmax = -1e30f;
#pragma unroll
      for (int c = 0; c < 2; ++c)
#pragma unroll
        for (int r = 0; r < 16; ++r) {
          const int crow = (r & 3) + 8 * (r >> 2) + 4 * hi;
          const int kk = t0 + 32 * c + crow;
          const bool ok = (kk <= iq) && (kk + LWIN >= iq);
          const float v = ok ? xv[c][r] : -1e30f;
          pa[c][r] = v;
          pmax = fmaxf(pmax, v);
        }
      pmax = fmaxf(pmax, __shfl_xor(pmax, 32));
      const float mn = fmaxf(m1, pmax);
      const float f = __expf(m1 - mn);
      m1 = mn;
      float sum = 0.f;
#pragma unroll
      for (int c = 0; c < 2; ++c)
#pragma unroll
        for (int r = 0; r < 16; ++r) {
          const float p = (pa[c][r] > -0.5e30f) ? __expf(pa[c][r] - mn) : 0.f;
          pa[c][r] = p;
          sum += p;
        }
      sum += __shfl_xor(sum, 32);
      l1 = l1 * f + sum;
      u32 Pp[2][8];
#pragma unroll
      for (int c = 0; c < 2; ++c)
#pragma unroll
        for (int w = 0; w < 8; ++w)
          Pp[c][w] = pk2(pa[c][2 * w], pa[c][2 * w + 1]);
#pragma unroll
      for (int r = 0; r < 16; ++r) {
        const float fq = __shfl(f, (r & 3) + 8 * (r >> 2) + 4 * hi);
        O1a[r] *= fq;
        O1b[r] *= fq;
      }
#pragma unroll
      for (int c = 0; c < 2; ++c)
#pragma unroll
        for (int h16 = 0; h16 < 2; ++h16) {
          F4 a;
          a.u = (u32x4){Pp[c][4 * h16 + 0], Pp[c][4 * h16 + 1],
                        Pp[c][4 * h16 + 2], Pp[c][4 * h16 + 3]};
          const int kb4 = 2 * c + h16;
          O1a = __builtin_amdgcn_mfma_f32_32x32x16_bf16(a.h, va[kb4].h, O1a, 0, 0, 0);
          O1b = __builtin_amdgcn_mfma_f32_32x32x16_bf16(a.h, vbf[kb4].h, O1b, 0, 0, 0);
        }
    }
  }

  // ---- epilogue: combine streams, write [B,T,NH*HD]
  const float wlr = 1.f / (1.f + __expf(-lwp[0]));
  const float wgr = 1.f / (1.f + __expf(-gwp[0]));
  const float wl = wlr / (wlr + wgr);
  const float wg = wgr / (wlr + wgr);
#pragma unroll
  for (int r = 0; r < 16; ++r) {
    const int crow = (r & 3) + 8 * (r >> 2) + 4 * hi;
    const float l1q = __shfl(l1, crow);
    const float l2q = __shfl(l2, crow);
    const int qrow = r0 + wv * 32 + crow;
    const size_t base = (size_t)(bb * TT + qrow) * CC + hh * 64;
    attnout[base + l31]      = wl * O1a[r] / l1q + wg * O2a[r] / l2q;
    attnout[base + 32 + l31] = wl * O1b[r] / l1q + wg * O2b[r] / l2q;
  }
}

// ---------------------------------------------------------------- launch
extern "C" void kernel_launch(void* const* d_in, const int* in_sizes, int n_in,
                              void* d_out, int out_size, void* d_ws, size_t ws_size,
                              hipStream_t stream) {
  const float* x      = (const float*)d_in[0];
  const float* w_attn = (const float*)d_in[1];
  const float* b_attn = (const float*)d_in[2];
  const float* w_proj = (const float*)d_in[3];
  const float* b_proj = (const float*)d_in[4];
  const float* w_sel1 = (const float*)d_in[5];
  const float* b_sel1 = (const float*)d_in[6];
  const float* w_sel2 = (const float*)d_in[7];
  const float* b_sel2 = (const float*)d_in[8];
  const float* lw     = (const float*)d_in[9];
  const float* gw     = (const float*)d_in[10];
  float* out = (float*)d_out;

  float* qkv     = (float*)d_ws;
  float* gatebuf = qkv + (size_t)MROWS * 2304;
  float* attnout = gatebuf + MROWS;

  gemm_bias_kernel<<<dim3(2304 / 128, MROWS / 128), 256, 0, stream>>>(
      x, w_attn, b_attn, qkv, MROWS, 2304, CC);
  sel_kernel<<<dim3(MROWS / 8), 256, 0, stream>>>(
      x, w_sel1, b_sel1, w_sel2, b_sel2, gatebuf);
  attn_mfma_kernel<<<dim3(TT / QBA, BBATCH * NHEAD), 256, 0, stream>>>(
      qkv, gatebuf, lw, gw, attnout);
  gemm_bias_kernel<<<dim3(CC / 128, MROWS / 128), 256, 0, stream>>>(
      attnout, w_proj, b_proj, out, MROWS, CC, CC);
}

// Round 5
// 349.520 us; speedup vs baseline: 12.2355x; 1.9725x over previous
//
#include <hip/hip_runtime.h>
#include <cmath>

#define TT    2048
#define CC    768
#define NHEAD 12
#define LWIN  256
#define BBATCH 2
#define MROWS 4096   // B*T
#define QBA   128    // query rows per attention block (4 waves x 32)
#define KB    64     // keys per tile

typedef unsigned int u32;
typedef u32 u32x2 __attribute__((ext_vector_type(2)));
typedef u32 u32x4 __attribute__((ext_vector_type(4)));
typedef short bf16x8 __attribute__((ext_vector_type(8)));
typedef float f32x16 __attribute__((ext_vector_type(16)));

union F4 { u32x4 u; bf16x8 h; };

// round-to-nearest-even f32->bf16
__device__ __forceinline__ unsigned short b16(float a) {
  u32 u = __float_as_uint(a);
  return (unsigned short)((u + 0x7FFFu + ((u >> 16) & 1u)) >> 16);
}
__device__ __forceinline__ u32 pk2(float a, float b) {
  return (u32)b16(a) | ((u32)b16(b) << 16);
}

// ---------------------------------------------------------------- x -> bf16
__global__ __launch_bounds__(256) void cvt_bf16_kernel(
    const float* __restrict__ in, unsigned short* __restrict__ out, int n8) {
  const int i = blockIdx.x * 256 + threadIdx.x;
  if (i >= n8) return;
  const float4 a = *(const float4*)&in[(size_t)i * 8];
  const float4 b = *(const float4*)&in[(size_t)i * 8 + 4];
  u32x4 w = {pk2(a.x, a.y), pk2(a.z, a.w), pk2(b.x, b.y), pk2(b.z, b.w)};
  *(u32x4*)&out[(size_t)i * 8] = w;
}

// ---------------------------------------------------------------- W[K][N] f32 -> Wt[N][K] bf16
__global__ __launch_bounds__(256) void transpose_cvt_kernel(
    const float* __restrict__ W, unsigned short* __restrict__ Wt, int K, int N) {
  __shared__ float t[32][33];
  const int tid = threadIdx.x;
  const int n0 = blockIdx.x * 32, k0 = blockIdx.y * 32;
  const int r = tid >> 5, c = tid & 31;
#pragma unroll
  for (int rr = 0; rr < 4; ++rr)
    t[r + 8 * rr][c] = W[(size_t)(k0 + r + 8 * rr) * N + n0 + c];
  __syncthreads();
#pragma unroll
  for (int rr = 0; rr < 4; ++rr)
    Wt[(size_t)(n0 + r + 8 * rr) * K + k0 + c] = b16(t[c][r + 8 * rr]);
}

// ---------------------------------------------------------------- bf16 MFMA GEMM
// C[M][N] = A[M][K] @ Wt[N][K]^T + bias.  BM=128, BN=NT*32, BK=64, 4 waves.
// D[m=crow][n=lane&31]: A operand = X rows (m), B operand = Wt rows (n);
// k-slot symmetric fragments [k0+16s+8hi+e] for both operands.
template <int NT, bool OUTBF>
__global__ __launch_bounds__(256) void gemm_mfma_kernel(
    const unsigned short* __restrict__ A, const unsigned short* __restrict__ Bt,
    const float* __restrict__ bias, void* __restrict__ Cout,
    int M, int N, int K) {
  __shared__ alignas(16) unsigned short as_[128 * 64];
  __shared__ alignas(16) unsigned short bs_[NT * 32 * 64];
  const int tid = threadIdx.x;
  const int lane = tid & 63;
  const int wv = tid >> 6;
  const int hi = lane >> 5;
  const int l31 = lane & 31;
  const int m0 = blockIdx.y * 128, n0 = blockIdx.x * (NT * 32);

  u32x4 ar[4], br[NT];

#define G_ISSUE(K0)                                                           \
  do {                                                                        \
    _Pragma("unroll") for (int i = 0; i < 4; ++i) {                           \
      const int idx = tid + (i << 8);                                         \
      const int r = idx >> 3, c = idx & 7;                                    \
      ar[i] = *(const u32x4*)&A[(size_t)(m0 + r) * K + (K0) + c * 8];         \
    }                                                                         \
    _Pragma("unroll") for (int i = 0; i < NT; ++i) {                          \
      const int idx = tid + (i << 8);                                         \
      const int r = idx >> 3, c = idx & 7;                                    \
      br[i] = *(const u32x4*)&Bt[(size_t)(n0 + r) * K + (K0) + c * 8];        \
    }                                                                         \
  } while (0)

#define G_WRITE()                                                             \
  do {                                                                        \
    _Pragma("unroll") for (int i = 0; i < 4; ++i) {                           \
      const int idx = tid + (i << 8);                                         \
      const int r = idx >> 3, c = idx & 7;                                    \
      *(u32x4*)((char*)as_ + r * 128 + ((c ^ (r & 7)) << 4)) = ar[i];         \
    }                                                                         \
    _Pragma("unroll") for (int i = 0; i < NT; ++i) {                          \
      const int idx = tid + (i << 8);                                         \
      const int r = idx >> 3, c = idx & 7;                                    \
      *(u32x4*)((char*)bs_ + r * 128 + ((c ^ (r & 7)) << 4)) = br[i];         \
    }                                                                         \
  } while (0)

  f32x16 acc[NT];
#pragma unroll
  for (int nt = 0; nt < NT; ++nt)
#pragma unroll
    for (int r = 0; r < 16; ++r) acc[nt][r] = 0.f;

  G_ISSUE(0);
  G_WRITE();
  __syncthreads();

  const int arow = wv * 32 + l31;
  for (int k0 = 0; k0 < K; k0 += 64) {
    if (k0 + 64 < K) G_ISSUE(k0 + 64);
#pragma unroll
    for (int s = 0; s < 4; ++s) {
      F4 af;
      af.u = *(const u32x4*)((const char*)as_ + arow * 128 +
                             (((2 * s + hi) ^ (arow & 7)) << 4));
#pragma unroll
      for (int nt = 0; nt < NT; ++nt) {
        F4 bf;
        bf.u = *(const u32x4*)((const char*)bs_ + (nt * 32 + l31) * 128 +
                               (((2 * s + hi) ^ (l31 & 7)) << 4));
        acc[nt] = __builtin_amdgcn_mfma_f32_32x32x16_bf16(af.h, bf.h, acc[nt], 0, 0, 0);
      }
    }
    __syncthreads();
    if (k0 + 64 < K) G_WRITE();
    __syncthreads();
  }

#pragma unroll
  for (int nt = 0; nt < NT; ++nt)
#pragma unroll
    for (int r = 0; r < 16; ++r) {
      const int m = m0 + wv * 32 + (r & 3) + 8 * (r >> 2) + 4 * hi;
      const int n = n0 + nt * 32 + l31;
      const float v = acc[nt][r] + bias[n];
      if (OUTBF)
        ((unsigned short*)Cout)[(size_t)m * N + n] = b16(v);
      else
        ((float*)Cout)[(size_t)m * N + n] = v;
    }
#undef G_ISSUE
#undef G_WRITE
}

// ---------------------------------------------------------------- selectivity gate (verified r1)
__global__ __launch_bounds__(256) void sel_kernel(
    const float* __restrict__ x, const float* __restrict__ w1,
    const float* __restrict__ b1, const float* __restrict__ w2,
    const float* __restrict__ b2, float* __restrict__ gate) {
  __shared__ alignas(16) float xs[8][768];
  __shared__ float gh[8][192];
  const int r0 = blockIdx.x * 8;
  const int tid = threadIdx.x;
#pragma unroll
  for (int idx = tid; idx < 8 * 192; idx += 256) {
    const int r = idx / 192, d4 = idx % 192;
    *(float4*)&xs[r][d4 << 2] =
        *(const float4*)&x[(size_t)(r0 + r) * 768 + (d4 << 2)];
  }
  __syncthreads();
  if (tid < 192) {
    float h[8];
#pragma unroll
    for (int r = 0; r < 8; ++r) h[r] = b1[tid];
#pragma unroll 4
    for (int d = 0; d < 768; ++d) {
      const float w = w1[d * 192 + tid];
#pragma unroll
      for (int r = 0; r < 8; ++r) h[r] = fmaf(xs[r][d], w, h[r]);
    }
#pragma unroll
    for (int r = 0; r < 8; ++r) {
      const float v = h[r];
      gh[r][tid] = 0.5f * v * (1.f + erff(v * 0.70710678118654752f));
    }
  }
  __syncthreads();
  if (tid < 8) {
    float s = b2[0];
    for (int j = 0; j < 192; ++j) s = fmaf(gh[tid][j], w2[j], s);
    const float sel = 1.f / (1.f + __expf(-s));
    gate[r0 + tid] = 0.2f + 0.8f * sel;
  }
}

// ---------------------------------------------------------------- MFMA fused attention
// r4-verified math; now: bf16 qkv input, Q frags direct from global,
// T14 async staging (issue loads pre-compute, LDS write post-barrier),
// reversed q-tile order, bf16 attnout output.
__global__ __launch_bounds__(256) void attn_mfma_kernel(
    const unsigned short* __restrict__ qkvb, const float* __restrict__ gate,
    const float* __restrict__ lwp, const float* __restrict__ gwp,
    unsigned short* __restrict__ attnout) {
  __shared__ alignas(16) unsigned short k_s[KB * 64];   // bf16, swizzled
  __shared__ alignas(16) unsigned short vt_s[64 * 68];  // V^T: row=d (68 u16)
  __shared__ float g_s[KB];

  const int tid = threadIdx.x;
  const int lane = tid & 63;
  const int wv = tid >> 6;
  const int hi = lane >> 5;
  const int l31 = lane & 31;
  const int bh = blockIdx.y;
  const int bb = bh / NHEAD;
  const int hh = bh % NHEAD;
  const int qt = (TT / QBA - 1) - blockIdx.x;   // heavy blocks first
  const int r0 = qt * QBA;
  const int iq = r0 + wv * 32 + l31;

  // Q fragments straight from global (bf16)
  bf16x8 qf[4];
  {
    const size_t qrow = (size_t)(bb * TT + r0 + wv * 32 + l31) * 2304 + hh * 64;
#pragma unroll
    for (int s = 0; s < 4; ++s) {
      F4 f;
      f.u = *(const u32x4*)&qkvb[qrow + 16 * s + 8 * hi];
      qf[s] = f.h;
    }
  }

  // per-lane V^T read bases: d = l31 (O-a) and 32+l31 (O-b), +8B for hi
  const char* vb0 = (const char*)vt_s + (size_t)l31 * 136 + hi * 8;
  const char* vb1 = vb0 + 32 * 136;

  u32x4 kr[2], vr[2];
  float gr = 0.f;

#define A_ISSUE(T0)                                                            \
  do {                                                                         \
    _Pragma("unroll") for (int i = 0; i < 2; ++i) {                            \
      const int idx = tid + (i << 8);                                          \
      const int r = idx >> 3, c = idx & 7;                                     \
      const size_t base = (size_t)(bb * TT + (T0) + r) * 2304 + hh * 64 + c * 8; \
      kr[i] = *(const u32x4*)&qkvb[base + 768];                                \
      vr[i] = *(const u32x4*)&qkvb[base + 1536];                               \
    }                                                                          \
    if (tid < KB) gr = gate[bb * TT + (T0) + tid];                             \
  } while (0)

#define A_WRITE()                                                              \
  do {                                                                         \
    _Pragma("unroll") for (int i = 0; i < 2; ++i) {                            \
      const int idx = tid + (i << 8);                                          \
      const int r = idx >> 3, c = idx & 7;                                     \
      *(u32x4*)((char*)k_s + r * 128 + ((c ^ (r & 7)) << 4)) = kr[i];          \
      const int d0 = c * 8;                                                    \
      vt_s[(d0 + 0) * 68 + r] = (unsigned short)(vr[i].x & 0xffff);            \
      vt_s[(d0 + 1) * 68 + r] = (unsigned short)(vr[i].x >> 16);               \
      vt_s[(d0 + 2) * 68 + r] = (unsigned short)(vr[i].y & 0xffff);            \
      vt_s[(d0 + 3) * 68 + r] = (unsigned short)(vr[i].y >> 16);               \
      vt_s[(d0 + 4) * 68 + r] = (unsigned short)(vr[i].z & 0xffff);            \
      vt_s[(d0 + 5) * 68 + r] = (unsigned short)(vr[i].z >> 16);               \
      vt_s[(d0 + 6) * 68 + r] = (unsigned short)(vr[i].w & 0xffff);            \
      vt_s[(d0 + 7) * 68 + r] = (unsigned short)(vr[i].w >> 16);               \
    }                                                                          \
    if (tid < KB) g_s[tid] = gr;                                               \
  } while (0)

  float m1 = -1e30f, l1 = 0.f, m2 = -1e30f, l2 = 0.f;
  f32x16 O1a, O1b, O2a, O2b;
#pragma unroll
  for (int r = 0; r < 16; ++r) { O1a[r] = 0.f; O1b[r] = 0.f; O2a[r] = 0.f; O2b[r] = 0.f; }

  const int nt = (r0 + QBA) >> 6;
  A_ISSUE(0);
  A_WRITE();
  __syncthreads();

  for (int t = 0; t < nt; ++t) {
    const int t0 = t << 6;
    if (t + 1 < nt) A_ISSUE(t0 + 64);

    // ---- QK^T
    f32x16 S0, S1;
#pragma unroll
    for (int r = 0; r < 16; ++r) { S0[r] = 0.f; S1[r] = 0.f; }
#pragma unroll
    for (int s = 0; s < 4; ++s) {
      const int blk = (2 * s + hi) ^ (l31 & 7);
      F4 f0, f1;
      f0.u = *(const u32x4*)((const char*)k_s + l31 * 128 + (blk << 4));
      f1.u = *(const u32x4*)((const char*)k_s + (32 + l31) * 128 + (blk << 4));
      S0 = __builtin_amdgcn_mfma_f32_32x32x16_bf16(f0.h, qf[s], S0, 0, 0, 0);
      S1 = __builtin_amdgcn_mfma_f32_32x32x16_bf16(f1.h, qf[s], S1, 0, 0, 0);
    }

    // ---- V fragments: per kb4, keys 16kb4+4hi+{0..3} and +8 at fixed d
    F4 va[4], vbf[4];
#pragma unroll
    for (int kb4 = 0; kb4 < 4; ++kb4) {
      const u32x2 a0 = *(const u32x2*)(vb0 + 32 * kb4);
      const u32x2 a1 = *(const u32x2*)(vb0 + 32 * kb4 + 16);
      va[kb4].u = (u32x4){a0.x, a0.y, a1.x, a1.y};
      const u32x2 c0 = *(const u32x2*)(vb1 + 32 * kb4);
      const u32x2 c1 = *(const u32x2*)(vb1 + 32 * kb4 + 16);
      vbf[kb4].u = (u32x4){c0.x, c0.y, c1.x, c1.y};
    }

    float xv[2][16];
#pragma unroll
    for (int r = 0; r < 16; ++r) { xv[0][r] = S0[r] * 0.125f; xv[1][r] = S1[r] * 0.125f; }

    // ================= stream 2: causal, gate-modulated =================
    {
      float pa[2][16];
      float pmax = -1e30f;
#pragma unroll
      for (int c = 0; c < 2; ++c)
#pragma unroll
        for (int r = 0; r < 16; ++r) {
          const int crow = (r & 3) + 8 * (r >> 2) + 4 * hi;
          const int kk = t0 + 32 * c + crow;
          const float g = g_s[32 * c + crow];
          const float v = (kk <= iq) ? xv[c][r] * g : -1e30f;
          pa[c][r] = v;
          pmax = fmaxf(pmax, v);
        }
      pmax = fmaxf(pmax, __shfl_xor(pmax, 32));
      const float mn = fmaxf(m2, pmax);
      const float f = __expf(m2 - mn);
      m2 = mn;
      float sum = 0.f;
#pragma unroll
      for (int c = 0; c < 2; ++c)
#pragma unroll
        for (int r = 0; r < 16; ++r) {
          const float p = (pa[c][r] > -0.5e30f) ? __expf(pa[c][r] - mn) : 0.f;
          pa[c][r] = p;
          sum += p;
        }
      sum += __shfl_xor(sum, 32);
      l2 = l2 * f + sum;
      u32 Pp[2][8];
#pragma unroll
      for (int c = 0; c < 2; ++c)
#pragma unroll
        for (int w = 0; w < 8; ++w)
          Pp[c][w] = pk2(pa[c][2 * w], pa[c][2 * w + 1]);
#pragma unroll
      for (int r = 0; r < 16; ++r) {
        const float fq = __shfl(f, (r & 3) + 8 * (r >> 2) + 4 * hi);
        O2a[r] *= fq;
        O2b[r] *= fq;
      }
#pragma unroll
      for (int c = 0; c < 2; ++c)
#pragma unroll
        for (int h16 = 0; h16 < 2; ++h16) {
          F4 a;
          a.u = (u32x4){Pp[c][4 * h16 + 0], Pp[c][4 * h16 + 1],
                        Pp[c][4 * h16 + 2], Pp[c][4 * h16 + 3]};
          const int kb4 = 2 * c + h16;
          O2a = __builtin_amdgcn_mfma_f32_32x32x16_bf16(a.h, va[kb4].h, O2a, 0, 0, 0);
          O2b = __builtin_amdgcn_mfma_f32_32x32x16_bf16(a.h, vbf[kb4].h, O2b, 0, 0, 0);
        }
    }

    // ================= stream 1: local window, raw scores =================
    if (t0 + 63 >= r0 + wv * 32 - LWIN) {
      float pa[2][16];
      float pmax = -1e30f;
#pragma unroll
      for (int c = 0; c < 2; ++c)
#pragma unroll
        for (int r = 0; r < 16; ++r) {
          const int crow = (r & 3) + 8 * (r >> 2) + 4 * hi;
          const int kk = t0 + 32 * c + crow;
          const bool ok = (kk <= iq) && (kk + LWIN >= iq);
          const float v = ok ? xv[c][r] : -1e30f;
          pa[c][r] = v;
          pmax = fmaxf(pmax, v);
        }
      pmax = fmaxf(pmax, __shfl_xor(pmax, 32));
      const float mn = fmaxf(m1, pmax);
      const float f = __expf(m1 - mn);
      m1 = mn;
      float sum = 0.f;
#pragma unroll
      for (int c = 0; c < 2; ++c)
#pragma unroll
        for (int r = 0; r < 16; ++r) {
          const float p = (pa[c][r] > -0.5e30f) ? __expf(pa[c][r] - mn) : 0.f;
          pa[c][r] = p;
          sum += p;
        }
      sum += __shfl_xor(sum, 32);
      l1 = l1 * f + sum;
      u32 Pp[2][8];
#pragma unroll
      for (int c = 0; c < 2; ++c)
#pragma unroll
        for (int w = 0; w < 8; ++w)
          Pp[c][w] = pk2(pa[c][2 * w], pa[c][2 * w + 1]);
#pragma unroll
      for (int r = 0; r < 16; ++r) {
        const float fq = __shfl(f, (r & 3) + 8 * (r >> 2) + 4 * hi);
        O1a[r] *= fq;
        O1b[r] *= fq;
      }
#pragma unroll
      for (int c = 0; c < 2; ++c)
#pragma unroll
        for (int h16 = 0; h16 < 2; ++h16) {
          F4 a;
          a.u = (u32x4){Pp[c][4 * h16 + 0], Pp[c][4 * h16 + 1],
                        Pp[c][4 * h16 + 2], Pp[c][4 * h16 + 3]};
          const int kb4 = 2 * c + h16;
          O1a = __builtin_amdgcn_mfma_f32_32x32x16_bf16(a.h, va[kb4].h, O1a, 0, 0, 0);
          O1b = __builtin_amdgcn_mfma_f32_32x32x16_bf16(a.h, vbf[kb4].h, O1b, 0, 0, 0);
        }
    }

    __syncthreads();
    if (t + 1 < nt) A_WRITE();
    __syncthreads();
  }
#undef A_ISSUE
#undef A_WRITE

  // ---- epilogue: combine streams, write bf16 [B,T,NH*HD]
  const float wlr = 1.f / (1.f + __expf(-lwp[0]));
  const float wgr = 1.f / (1.f + __expf(-gwp[0]));
  const float wl = wlr / (wlr + wgr);
  const float wg = wgr / (wlr + wgr);
#pragma unroll
  for (int r = 0; r < 16; ++r) {
    const int crow = (r & 3) + 8 * (r >> 2) + 4 * hi;
    const float l1q = __shfl(l1, crow);
    const float l2q = __shfl(l2, crow);
    const int qrow = r0 + wv * 32 + crow;
    const size_t base = (size_t)(bb * TT + qrow) * CC + hh * 64;
    attnout[base + l31]      = b16(wl * O1a[r] / l1q + wg * O2a[r] / l2q);
    attnout[base + 32 + l31] = b16(wl * O1b[r] / l1q + wg * O2b[r] / l2q);
  }
}

// ---------------------------------------------------------------- launch
extern "C" void kernel_launch(void* const* d_in, const int* in_sizes, int n_in,
                              void* d_out, int out_size, void* d_ws, size_t ws_size,
                              hipStream_t stream) {
  const float* x      = (const float*)d_in[0];
  const float* w_attn = (const float*)d_in[1];
  const float* b_attn = (const float*)d_in[2];
  const float* w_proj = (const float*)d_in[3];
  const float* b_proj = (const float*)d_in[4];
  const float* w_sel1 = (const float*)d_in[5];
  const float* b_sel1 = (const float*)d_in[6];
  const float* w_sel2 = (const float*)d_in[7];
  const float* b_sel2 = (const float*)d_in[8];
  const float* lw     = (const float*)d_in[9];
  const float* gw     = (const float*)d_in[10];
  float* out = (float*)d_out;

  // workspace carve (u16 units)
  unsigned short* qkvb  = (unsigned short*)d_ws;                 // 4096*2304
  unsigned short* xb    = qkvb + (size_t)MROWS * 2304;           // 4096*768
  unsigned short* wta   = xb + (size_t)MROWS * 768;              // 2304*768
  unsigned short* wtp   = wta + (size_t)2304 * 768;              // 768*768
  unsigned short* aob   = wtp + (size_t)768 * 768;               // 4096*768
  float* gatebuf        = (float*)(aob + (size_t)MROWS * 768);   // 4096

  cvt_bf16_kernel<<<(MROWS * 768 / 8 + 255) / 256, 256, 0, stream>>>(
      x, xb, MROWS * 768 / 8);
  transpose_cvt_kernel<<<dim3(2304 / 32, 768 / 32), 256, 0, stream>>>(
      w_attn, wta, 768, 2304);
  transpose_cvt_kernel<<<dim3(768 / 32, 768 / 32), 256, 0, stream>>>(
      w_proj, wtp, 768, 768);
  sel_kernel<<<dim3(MROWS / 8), 256, 0, stream>>>(
      x, w_sel1, b_sel1, w_sel2, b_sel2, gatebuf);
  gemm_mfma_kernel<4, true><<<dim3(2304 / 128, MROWS / 128), 256, 0, stream>>>(
      xb, wta, b_attn, qkvb, MROWS, 2304, 768);
  attn_mfma_kernel<<<dim3(TT / QBA, BBATCH * NHEAD), 256, 0, stream>>>(
      qkvb, gatebuf, lw, gw, aob);
  gemm_mfma_kernel<2, false><<<dim3(768 / 64, MROWS / 128), 256, 0, stream>>>(
      aob, wtp, b_proj, out, MROWS, 768, 768);
}